// Round 15
// baseline (503.719 us; speedup 1.0000x reference)
//
#include <hip/hip_runtime.h>
#include <math.h>

#define NR 65536
#define NS 2097152
#define GRID 2048          // persistent blocks; each loops NS/256/GRID = 4 tiles

typedef __attribute__((ext_vector_type(4))) float f32x4;
typedef __attribute__((ext_vector_type(2))) float f32x2;
typedef __attribute__((ext_vector_type(8))) short short8;

// LDS: row = 32 dwords (one sample's 64 bf16 acts), group = 16 rows = 512 dwords,
// wave = 4 groups = 2048 dwords, block = 4 waves = 8192 dwords = 32768 B exactly.
// Chunk-XOR swizzle: 16B chunk c of sample s stored at chunk (c ^ (s&7)).

// ---------------- workspace layout ----------------
// [0, NS*8)                 : uint2 rgba (bf16 r,g | b,alpha) per sample
// [NS*8, +NS*4)             : float tmid[NS]
// [NS*12, +NR*8)            : int start[NR], end[NR]
// [NS*12+NR*8, +40KB)       : uint4 wfrag[40*64]  (A-fragments, bf16, W^T)
// [.. +40KB, +4MB)          : uint4 dtab[NR*4]    (per-ray dir-enc, bf16)

// Native bf16 conversion (RNE fptrunc) — compiler lowers to HW cvt.
__device__ __forceinline__ uint packbf(float a, float b) {
    __bf16 lo = (__bf16)a, hi = (__bf16)b;
    ushort ul = __builtin_bit_cast(ushort, lo);
    ushort uh = __builtin_bit_cast(ushort, hi);
    return (uint)ul | ((uint)uh << 16);
}
__device__ __forceinline__ float bflo(uint u) { return __builtin_bit_cast(float, u << 16); }

// Merged setup: blocks 0-255 direnc, 256-511 init_bounds, 512-521 build_frags.
__global__ void setup_kernel(const float* __restrict__ viewdirs,
                             uint4* __restrict__ dtab,
                             int* __restrict__ start, int* __restrict__ end,
                             const float* __restrict__ W1, const float* __restrict__ W2,
                             const float* __restrict__ Wf, const float* __restrict__ Wr1,
                             const float* __restrict__ Wd, const float* __restrict__ Wr2,
                             uint4* __restrict__ wfrag) {
    int b = blockIdx.x, tid = threadIdx.x;
    if (b < 256) {
        // ---- per-ray dir posenc -> 4 uint4 per ray ----
        int r = b * 256 + tid;
        float dx = viewdirs[3 * r + 0], dy = viewdirs[3 * r + 1], dz = viewdirs[3 * r + 2];
        float de[32];
        de[0] = dx; de[1] = dy; de[2] = dz;
        float sx = __sinf(dx), cx = __cosf(dx);
        float sy = __sinf(dy), cy = __cosf(dy);
        float sz = __sinf(dz), cz = __cosf(dz);
        #pragma unroll
        for (int l = 0; l < 4; ++l) {
            de[3 + 6 * l + 0] = sx; de[3 + 6 * l + 1] = sy; de[3 + 6 * l + 2] = sz;
            de[3 + 6 * l + 3] = cx; de[3 + 6 * l + 4] = cy; de[3 + 6 * l + 5] = cz;
            float nsx = 2.0f * sx * cx, nsy = 2.0f * sy * cy, nsz = 2.0f * sz * cz;
            cx = fmaf(-2.0f * sx, sx, 1.0f);
            cy = fmaf(-2.0f * sy, sy, 1.0f);
            cz = fmaf(-2.0f * sz, sz, 1.0f);
            sx = nsx; sy = nsy; sz = nsz;
        }
        #pragma unroll
        for (int k = 27; k < 32; ++k) de[k] = 0.0f;
        #pragma unroll
        for (int c = 0; c < 4; ++c) {
            uint4 q = make_uint4(packbf(de[8 * c + 0], de[8 * c + 1]),
                                 packbf(de[8 * c + 2], de[8 * c + 3]),
                                 packbf(de[8 * c + 4], de[8 * c + 5]),
                                 packbf(de[8 * c + 6], de[8 * c + 7]));
            dtab[(size_t)r * 4 + c] = q;
        }
    } else if (b < 512) {
        int r = (b - 256) * 256 + tid;
        start[r] = 0; end[r] = 0;
    } else {
        // ---- build A-fragments (W^T), order: L1 0-7, L2 8-15, Wf 16-23,
        //      Wr1 24-35, Wd 36-37, Wr2 38-39 ----
        int t = (b - 512) * 256 + tid;
        if (t >= 40 * 64) return;
        int f = t >> 6, lane = t & 63;
        int c = lane & 15;
        uint q[4];
        if (f < 36) {
            const float* W; int kmax, fl;
            if (f < 8)       { W = W1;  kmax = 63; fl = f; }
            else if (f < 16) { W = W2;  kmax = 64; fl = f - 8; }
            else if (f < 24) { W = Wf;  kmax = 64; fl = f - 16; }
            else             { W = Wr1; kmax = 91; fl = f - 24; }
            int ks = fl >> 2, ft = fl & 3;
            int n = ft * 16 + c;
            int kb = ks * 32 + ((lane >> 4) * 8);
            #pragma unroll
            for (int j = 0; j < 4; ++j) {
                int k0 = kb + 2 * j, k1 = k0 + 1;
                float v0 = (k0 < kmax) ? W[k0 * 64 + n] : 0.0f;
                float v1 = (k1 < kmax) ? W[k1 * 64 + n] : 0.0f;
                q[j] = packbf(v0, v1);
            }
        } else if (f < 38) {          // sigma tile: A[m][k] = (m==0) ? Wd[k] : 0
            int kb = (f - 36) * 32 + ((lane >> 4) * 8);
            #pragma unroll
            for (int j = 0; j < 4; ++j) {
                float v0 = (c == 0) ? Wd[kb + 2 * j] : 0.0f;
                float v1 = (c == 0) ? Wd[kb + 2 * j + 1] : 0.0f;
                q[j] = packbf(v0, v1);
            }
        } else {                      // rgb tile: A[m][k] = (m<3) ? Wr2[k*3+m] : 0
            int kb = (f - 38) * 32 + ((lane >> 4) * 8);
            #pragma unroll
            for (int j = 0; j < 4; ++j) {
                float v0 = (c < 3) ? Wr2[(kb + 2 * j) * 3 + c] : 0.0f;
                float v1 = (c < 3) ? Wr2[(kb + 2 * j + 1) * 3 + c] : 0.0f;
                q[j] = packbf(v0, v1);
            }
        }
        wfrag[(size_t)f * 64 + lane] = make_uint4(q[0], q[1], q[2], q[3]);
    }
}

// ro[ks]: dword addr of logical chunk (g+4ks) of row s, group 0 (swizzled).
// wo[ft]: dword addr of writeback b64 (dwords 8ft+2g..+1) of row s, group 0.
template <int KS, bool RELU, bool SIGMA, bool DIRB>
__device__ __forceinline__ void dense_layer(uint* S, const uint4* __restrict__ wfrag,
                                            int fb, const float* __restrict__ bias,
                                            float bd0, const uint (&ro)[2],
                                            const uint (&wo)[4],
                                            int lane, const uint4 (&dirB)[4],
                                            float* sigout) {
    const int g = lane >> 4;
    uint4 wf[KS * 4];
    #pragma unroll
    for (int i = 0; i < KS * 4; ++i) wf[i] = wfrag[(size_t)(fb + i) * 64 + lane];
    uint4 wsg[2];
    if constexpr (SIGMA) {
        wsg[0] = wfrag[36 * 64 + lane];
        wsg[1] = wfrag[37 * 64 + lane];
    }
    float4 bfr[4];
    #pragma unroll
    for (int ft = 0; ft < 4; ++ft)
        bfr[ft] = *(const float4*)(bias + 16 * ft + 4 * g);

    #pragma unroll
    for (int st = 0; st < 4; ++st) {
        const uint stoff = (uint)st * 512u;
        uint4 B[KS];
        #pragma unroll
        for (int ks = 0; ks < KS; ++ks) {
            if (DIRB && ks == KS - 1) B[ks] = dirB[st];
            else B[ks] = *(const uint4*)&S[ro[ks] + stoff];             // ds_read_b128
        }
        f32x4 acc[4];
        #pragma unroll
        for (int ft = 0; ft < 4; ++ft)
            acc[ft] = (f32x4){bfr[ft].x, bfr[ft].y, bfr[ft].z, bfr[ft].w};
        f32x4 sacc;
        if constexpr (SIGMA) sacc = (f32x4){(g == 0) ? bd0 : 0.0f, 0.0f, 0.0f, 0.0f};
        #pragma unroll
        for (int ks = 0; ks < KS; ++ks) {
            short8 bv = __builtin_bit_cast(short8, B[ks]);
            #pragma unroll
            for (int ft = 0; ft < 4; ++ft)
                acc[ft] = __builtin_amdgcn_mfma_f32_16x16x32_bf16(
                    __builtin_bit_cast(short8, wf[ks * 4 + ft]), bv, acc[ft], 0, 0, 0);
            if constexpr (SIGMA)
                sacc = __builtin_amdgcn_mfma_f32_16x16x32_bf16(
                    __builtin_bit_cast(short8, wsg[ks]), bv, sacc, 0, 0, 0);
        }
        // D layout: col = lane&15 = sample, row = 4g + reg = out-feature.
        #pragma unroll
        for (int ft = 0; ft < 4; ++ft) {
            f32x2 lo = {acc[ft][0], acc[ft][1]};
            f32x2 hi = {acc[ft][2], acc[ft][3]};
            if constexpr (RELU) {
                lo = __builtin_elementwise_max(lo, (f32x2){0.0f, 0.0f});  // v_pk_max_f32
                hi = __builtin_elementwise_max(hi, (f32x2){0.0f, 0.0f});
            }
            uint2 v = make_uint2(packbf(lo.x, lo.y), packbf(hi.x, hi.y));
            *(uint2*)&S[wo[ft] + stoff] = v;                            // ds_write_b64
        }
        if constexpr (SIGMA) sigout[st] = sacc[0];
    }
}

__global__ __launch_bounds__(256, 4) void fused_mlp(
    const float* __restrict__ rays_o, const float* __restrict__ viewdirs,
    const float* __restrict__ t_starts, const float* __restrict__ t_ends,
    const float* __restrict__ b1, const float* __restrict__ b2,
    const float* __restrict__ bd, const float* __restrict__ bf_,
    const float* __restrict__ br1, const float* __restrict__ br2,
    const int* __restrict__ ridx, const uint4* __restrict__ wfrag,
    const uint4* __restrict__ dtab, uint2* __restrict__ rgba,
    float* __restrict__ tmarr, int* __restrict__ start, int* __restrict__ end)
{
    __shared__ uint S[8192];          // 32768 B exactly

    const int tid = threadIdx.x;
    const int w = tid >> 6, lane = tid & 63;
    const int g = lane >> 4, s = lane & 15;
    const uint sm = (uint)(s & 7);
    const uint wgb = (uint)w * 2048u;                 // wave base (4 groups x 512)
    const uint rowb = wgb + (uint)s * 32u;            // row s of group 0

    // Per-thread swizzled base addresses (tile-independent):
    const uint ownbase = wgb + (uint)g * 512u + (uint)s * 32u;  // own sample's row
    uint ro[2], wo[4];
    #pragma unroll
    for (int ks = 0; ks < 2; ++ks)
        ro[ks] = rowb + 4u * (((uint)(g + 4 * ks)) ^ sm);
    #pragma unroll
    for (int ft = 0; ft < 4; ++ft)
        wo[ft] = rowb + 4u * (((uint)(2 * ft + (g >> 1))) ^ sm) + 2u * (uint)(g & 1);

    float bd0 = bd[0];

    // ---- persistent loop: each block processes NS/256/GRID tiles ----
    for (int tile = blockIdx.x; tile < NS / 256; tile += GRID) {
        const int sb0 = tile * 256 + w * 64;

        // ---- ridx for this thread's 4 B-samples (st, s) + own sample (st=g) ----
        int ridx4[4];
        #pragma unroll
        for (int st = 0; st < 4; ++st) ridx4[st] = ridx[sb0 + st * 16 + s];
        uint4 dirB[4];
        #pragma unroll
        for (int st = 0; st < 4; ++st) dirB[st] = dtab[(size_t)ridx4[st] * 4 + g];

        const int si = sb0 + g * 16 + s;
        const int rr = ridx4[g];

        // ---- segment bounds for own sample (folded find_bounds) ----
        {
            int r_prev = ridx[(si == 0) ? 0 : si - 1];
            int r_next = ridx[(si == NS - 1) ? NS - 1 : si + 1];
            if (si == 0 || r_prev != rr) start[rr] = si;
            if (si == NS - 1 || r_next != rr) end[rr] = si + 1;
        }

        float ts = t_starts[si], te = t_ends[si];
        float tm = 0.5f * (ts + te), dtv = te - ts;
        float dx = viewdirs[3 * rr + 0], dy = viewdirs[3 * rr + 1], dz = viewdirs[3 * rr + 2];
        float px = rays_o[3 * rr + 0] + dx * tm;
        float py = rays_o[3 * rr + 1] + dy * tm;
        float pz = rays_o[3 * rr + 2] + dz * tm;
        tmarr[si] = tm;                               // render reads this (coalesced)

        // ---- posenc(pts,10), x/y packed, z scalar -> 8 swizzled chunks ----
        {
            float enc[64];
            enc[0] = px; enc[1] = py; enc[2] = pz;
            f32x2 sxy = {__sinf(px), __sinf(py)};
            f32x2 cxy = {__cosf(px), __cosf(py)};
            float sz = __sinf(pz), cz = __cosf(pz);
            #pragma unroll
            for (int l = 0; l < 10; ++l) {
                enc[3 + 6 * l + 0] = sxy.x; enc[3 + 6 * l + 1] = sxy.y; enc[3 + 6 * l + 2] = sz;
                enc[3 + 6 * l + 3] = cxy.x; enc[3 + 6 * l + 4] = cxy.y; enc[3 + 6 * l + 5] = cz;
                f32x2 nsxy = 2.0f * sxy * cxy;
                cxy = 1.0f - 2.0f * sxy * sxy;
                float nsz = 2.0f * sz * cz;
                cz = fmaf(-2.0f * sz, sz, 1.0f);
                sxy = nsxy; sz = nsz;
            }
            enc[63] = 0.0f;
            #pragma unroll
            for (int ch = 0; ch < 8; ++ch) {
                uint4 q = make_uint4(packbf(enc[8 * ch + 0], enc[8 * ch + 1]),
                                     packbf(enc[8 * ch + 2], enc[8 * ch + 3]),
                                     packbf(enc[8 * ch + 4], enc[8 * ch + 5]),
                                     packbf(enc[8 * ch + 6], enc[8 * ch + 7]));
                *(uint4*)&S[ownbase + 4u * (((uint)ch) ^ sm)] = q;      // ds_write_b128
            }
        }

        float sig4[4];
        uint4 dummy[4];

        dense_layer<2, true,  false, false>(S, wfrag,  0, b1,  0.0f, ro, wo, lane, dummy, sig4);
        dense_layer<2, true,  false, false>(S, wfrag,  8, b2,  0.0f, ro, wo, lane, dummy, sig4);
        dense_layer<2, false, true,  false>(S, wfrag, 16, bf_, bd0,  ro, wo, lane, dummy, sig4);
        dense_layer<3, true,  false, true >(S, wfrag, 24, br1, 0.0f, ro, wo, lane, dirB, sig4);

        // ---- rgb tile + epilogue ----
        {
            uint4 wr0 = wfrag[38 * 64 + lane], wr1f = wfrag[39 * 64 + lane];
            float c0 = br2[0], c1 = br2[1], c2 = br2[2];
            #pragma unroll
            for (int st = 0; st < 4; ++st) {
                const uint stoff = (uint)st * 512u;
                uint4 B0 = *(const uint4*)&S[ro[0] + stoff];       // chunks g
                uint4 B1 = *(const uint4*)&S[ro[1] + stoff];       // chunks g+4
                f32x4 acc = (g == 0) ? (f32x4){c0, c1, c2, 0.0f}
                                     : (f32x4){0.0f, 0.0f, 0.0f, 0.0f};
                acc = __builtin_amdgcn_mfma_f32_16x16x32_bf16(
                    __builtin_bit_cast(short8, wr0), __builtin_bit_cast(short8, B0), acc, 0, 0, 0);
                acc = __builtin_amdgcn_mfma_f32_16x16x32_bf16(
                    __builtin_bit_cast(short8, wr1f), __builtin_bit_cast(short8, B1), acc, 0, 0, 0);
                // dtv of sample (st, lane&15) lives in lane st*16+(lane&15)
                float dte = __shfl(dtv, st * 16 + (lane & 15));
                if (lane < 16) {
                    float sg = fmaxf(sig4[st], 0.0f);
                    float alpha = 1.0f - __expf(-sg * dte);
                    float r0 = 1.0f / (1.0f + __expf(-acc[0]));
                    float r1 = 1.0f / (1.0f + __expf(-acc[1]));
                    float r2 = 1.0f / (1.0f + __expf(-acc[2]));
                    uint2 o;
                    o.x = packbf(r0, r1);
                    o.y = packbf(r2, alpha);
                    rgba[sb0 + st * 16 + lane] = o;
                }
            }
        }
    }
}

__global__ void render_kernel(const uint2* __restrict__ rgba,
                              const float* __restrict__ tmarr,
                              const int* __restrict__ start,
                              const int* __restrict__ end,
                              float* __restrict__ out)
{
    int r = blockIdx.x * blockDim.x + threadIdx.x;
    if (r >= NR) return;
    int sb = start[r], e = end[r];
    float T = 1.0f, c0 = 0.0f, c1 = 0.0f, c2 = 0.0f, op = 0.0f, dp = 0.0f;
    for (int i = sb; i < e; ++i) {
        uint2 q = rgba[i];
        float tmid = tmarr[i];
        float vr = bflo(q.x & 0xffffu), vg = bflo(q.x >> 16);
        float vb = bflo(q.y & 0xffffu), va = bflo(q.y >> 16);
        float wgt = T * va;
        c0 += wgt * vr; c1 += wgt * vg; c2 += wgt * vb;
        op += wgt; dp += wgt * tmid;
        T *= (1.0f - va);
    }
    float bg = 1.0f - op;
    c0 += bg; c1 += bg; c2 += bg;
    out[3 * r + 0] = c0;
    out[3 * r + 1] = c1;
    out[3 * r + 2] = c2;
    out[3 * NR + r] = op;
    out[4 * NR + r] = dp;
}

extern "C" void kernel_launch(void* const* d_in, const int* in_sizes, int n_in,
                              void* d_out, int out_size, void* d_ws, size_t ws_size,
                              hipStream_t stream) {
    const float* rays_o   = (const float*)d_in[0];
    const float* viewdirs = (const float*)d_in[1];
    const float* t_starts = (const float*)d_in[2];
    const float* t_ends   = (const float*)d_in[3];
    const float* W1  = (const float*)d_in[4];
    const float* b1  = (const float*)d_in[5];
    const float* W2  = (const float*)d_in[6];
    const float* b2  = (const float*)d_in[7];
    const float* Wd  = (const float*)d_in[8];
    const float* bd  = (const float*)d_in[9];
    const float* Wf  = (const float*)d_in[10];
    const float* bf_ = (const float*)d_in[11];
    const float* Wr1 = (const float*)d_in[12];
    const float* br1 = (const float*)d_in[13];
    const float* Wr2 = (const float*)d_in[14];
    const float* br2 = (const float*)d_in[15];
    const int* ridx  = (const int*)d_in[16];
    float* out = (float*)d_out;

    char* ws = (char*)d_ws;
    uint2* rgba  = (uint2*)ws;
    float* tmarr = (float*)(ws + (size_t)NS * 8);
    int* start   = (int*)(ws + (size_t)NS * 12);
    int* end     = start + NR;
    uint4* wfrag = (uint4*)(ws + (size_t)NS * 12 + (size_t)NR * 8);
    uint4* dtab  = (uint4*)(ws + (size_t)NS * 12 + (size_t)NR * 8 + 40 * 64 * 16);

    setup_kernel<<<522, 256, 0, stream>>>(viewdirs, dtab, start, end,
                                          W1, W2, Wf, Wr1, Wd, Wr2, wfrag);
    fused_mlp<<<GRID, 256, 0, stream>>>(
        rays_o, viewdirs, t_starts, t_ends,
        b1, b2, bd, bf_, br1, br2, ridx, wfrag, dtab, rgba, tmarr, start, end);
    render_kernel<<<NR / 256, 256, 0, stream>>>(rgba, tmarr, start, end, out);
}

// Round 16
// 133.697 us; speedup vs baseline: 3.7676x; 3.7676x over previous
//
#include <hip/hip_runtime.h>
#include <math.h>

#define NR 65536
#define NS 2097152

typedef __attribute__((ext_vector_type(4))) float f32x4;
typedef __attribute__((ext_vector_type(2))) float f32x2;
typedef __attribute__((ext_vector_type(8))) short short8;

// LDS: row = 32 dwords (one sample's 64 bf16 acts), group = 16 rows = 512 dwords,
// wave = 4 groups = 2048 dwords, block = 4 waves = 8192 dwords = 32768 B exactly.
// Chunk-XOR swizzle: 16B chunk c of sample s stored at chunk (c ^ (s&7)).
//
// Layer fusion: feat = h2@Wf + bf is LINEAR (no relu), so
//   hd = relu(h2@(Wf@Wr1a) + direnc@Wr1b + (bf@Wr1a + br1))
// -> precomputed W34 = Wf@Wr1a (64x64) and b34 = bf@Wr1a + br1; L3 eliminated.

// ---------------- workspace layout ----------------
// [0, NS*8)                 : uint2 rgba (bf16 r,g | b,alpha) per sample
// [NS*8, +NS*4)             : float tmid[NS]
// [NS*12, +NR*8)            : int start[NR], end[NR]
// [NS*12+NR*8, +32KB)       : uint4 wfrag[32*64]  (A-fragments, bf16, W^T)
//   frags: L1 0-7, L2 8-15, L34 W34 16-23, L34 Wr1b 24-27, sigma 28-29, rgb 30-31
// [.. +32KB, +256B)         : float b34[64]
// [.. +256B, +4MB)          : uint4 dtab[NR*4]    (per-ray dir-enc, bf16)

// Native bf16 conversion (RNE fptrunc) — compiler lowers to HW cvt.
__device__ __forceinline__ uint packbf(float a, float b) {
    __bf16 lo = (__bf16)a, hi = (__bf16)b;
    ushort ul = __builtin_bit_cast(ushort, lo);
    ushort uh = __builtin_bit_cast(ushort, hi);
    return (uint)ul | ((uint)uh << 16);
}
__device__ __forceinline__ float bflo(uint u) { return __builtin_bit_cast(float, u << 16); }

// Merged setup: blocks 0-255 direnc, 256-511 init_bounds, 512-519 build_frags,
// 520 b34.
__global__ void setup_kernel(const float* __restrict__ viewdirs,
                             uint4* __restrict__ dtab,
                             int* __restrict__ start, int* __restrict__ end,
                             const float* __restrict__ W1, const float* __restrict__ W2,
                             const float* __restrict__ Wf, const float* __restrict__ Wr1,
                             const float* __restrict__ Wd, const float* __restrict__ Wr2,
                             const float* __restrict__ bf_, const float* __restrict__ br1,
                             uint4* __restrict__ wfrag, float* __restrict__ b34) {
    int b = blockIdx.x, tid = threadIdx.x;
    if (b < 256) {
        // ---- per-ray dir posenc -> 4 uint4 per ray ----
        int r = b * 256 + tid;
        float dx = viewdirs[3 * r + 0], dy = viewdirs[3 * r + 1], dz = viewdirs[3 * r + 2];
        float de[32];
        de[0] = dx; de[1] = dy; de[2] = dz;
        float sx = __sinf(dx), cx = __cosf(dx);
        float sy = __sinf(dy), cy = __cosf(dy);
        float sz = __sinf(dz), cz = __cosf(dz);
        #pragma unroll
        for (int l = 0; l < 4; ++l) {
            de[3 + 6 * l + 0] = sx; de[3 + 6 * l + 1] = sy; de[3 + 6 * l + 2] = sz;
            de[3 + 6 * l + 3] = cx; de[3 + 6 * l + 4] = cy; de[3 + 6 * l + 5] = cz;
            float nsx = 2.0f * sx * cx, nsy = 2.0f * sy * cy, nsz = 2.0f * sz * cz;
            cx = fmaf(-2.0f * sx, sx, 1.0f);
            cy = fmaf(-2.0f * sy, sy, 1.0f);
            cz = fmaf(-2.0f * sz, sz, 1.0f);
            sx = nsx; sy = nsy; sz = nsz;
        }
        #pragma unroll
        for (int k = 27; k < 32; ++k) de[k] = 0.0f;
        #pragma unroll
        for (int c = 0; c < 4; ++c) {
            uint4 q = make_uint4(packbf(de[8 * c + 0], de[8 * c + 1]),
                                 packbf(de[8 * c + 2], de[8 * c + 3]),
                                 packbf(de[8 * c + 4], de[8 * c + 5]),
                                 packbf(de[8 * c + 6], de[8 * c + 7]));
            dtab[(size_t)r * 4 + c] = q;
        }
    } else if (b < 512) {
        int r = (b - 256) * 256 + tid;
        start[r] = 0; end[r] = 0;
    } else if (b < 520) {
        // ---- build A-fragments (W^T): lane holds A[m=16ft+c][k=32ks+g2*8+e] ----
        int t = (b - 512) * 256 + tid;          // t in [0, 2048) = 32 frags * 64
        int f = t >> 6, lane = t & 63;
        int c = lane & 15, g2 = lane >> 4;
        uint q[4];
        if (f < 16) {                           // L1 (W1, kmax 63) / L2 (W2, kmax 64)
            const float* W = (f < 8) ? W1 : W2;
            int kmax = (f < 8) ? 63 : 64;
            int fl = f & 7;
            int ks = fl >> 2, ft = fl & 3;
            int n = ft * 16 + c;
            int kb = ks * 32 + g2 * 8;
            #pragma unroll
            for (int j = 0; j < 4; ++j) {
                int k0 = kb + 2 * j, k1 = k0 + 1;
                float v0 = (k0 < kmax) ? W[k0 * 64 + n] : 0.0f;
                float v1 = (k1 < kmax) ? W[k1 * 64 + n] : 0.0f;
                q[j] = packbf(v0, v1);
            }
        } else if (f < 24) {                    // W34[k][m] = sum_p Wf[k][p]*Wr1[p][m]
            int fl = f - 16;
            int ks = fl >> 2, ft = fl & 3;
            int m = ft * 16 + c;
            int kb = ks * 32 + g2 * 8;
            #pragma unroll
            for (int j = 0; j < 4; ++j) {
                int k0 = kb + 2 * j, k1 = k0 + 1;
                float v0 = 0.0f, v1 = 0.0f;
                for (int p = 0; p < 64; ++p) {
                    float w = Wr1[p * 64 + m];
                    v0 = fmaf(Wf[k0 * 64 + p], w, v0);
                    v1 = fmaf(Wf[k1 * 64 + p], w, v1);
                }
                q[j] = packbf(v0, v1);
            }
        } else if (f < 28) {                    // Wr1b: rows 64..90 of Wr1 (dir part)
            int n = (f - 24) * 16 + c;
            int kb = 64 + g2 * 8;
            #pragma unroll
            for (int j = 0; j < 4; ++j) {
                int k0 = kb + 2 * j, k1 = k0 + 1;
                float v0 = (k0 < 91) ? Wr1[k0 * 64 + n] : 0.0f;
                float v1 = (k1 < 91) ? Wr1[k1 * 64 + n] : 0.0f;
                q[j] = packbf(v0, v1);
            }
        } else if (f < 30) {                    // sigma: A[m][k] = (m==0)?Wd[k]:0
            int kb = (f - 28) * 32 + g2 * 8;
            #pragma unroll
            for (int j = 0; j < 4; ++j) {
                float v0 = (c == 0) ? Wd[kb + 2 * j] : 0.0f;
                float v1 = (c == 0) ? Wd[kb + 2 * j + 1] : 0.0f;
                q[j] = packbf(v0, v1);
            }
        } else {                                // rgb: A[m][k] = (m<3)?Wr2[k*3+m]:0
            int kb = (f - 30) * 32 + g2 * 8;
            #pragma unroll
            for (int j = 0; j < 4; ++j) {
                float v0 = (c < 3) ? Wr2[(kb + 2 * j) * 3 + c] : 0.0f;
                float v1 = (c < 3) ? Wr2[(kb + 2 * j + 1) * 3 + c] : 0.0f;
                q[j] = packbf(v0, v1);
            }
        }
        wfrag[(size_t)f * 64 + lane] = make_uint4(q[0], q[1], q[2], q[3]);
    } else {
        // ---- b34[j] = br1[j] + sum_k bf_[k] * Wr1[k][j] ----
        if (tid < 64) {
            float acc = br1[tid];
            for (int k = 0; k < 64; ++k) acc = fmaf(bf_[k], Wr1[k * 64 + tid], acc);
            b34[tid] = acc;
        }
    }
}

// ro[ks]: dword addr of logical chunk (g+4ks) of row s, group 0 (swizzled).
// wo[ft]: dword addr of writeback b64 (dwords 8ft+2g..+1) of row s, group 0.
template <int KS, bool RELU, bool SIGMA, bool DIRB>
__device__ __forceinline__ void dense_layer(uint* S, const uint4* __restrict__ wfrag,
                                            int fb, const float* __restrict__ bias,
                                            float bd0, const uint (&ro)[2],
                                            const uint (&wo)[4],
                                            int lane, const uint4 (&dirB)[4],
                                            float* sigout) {
    const int g = lane >> 4;
    uint4 wf[KS * 4];
    #pragma unroll
    for (int i = 0; i < KS * 4; ++i) wf[i] = wfrag[(size_t)(fb + i) * 64 + lane];
    uint4 wsg[2];
    if constexpr (SIGMA) {
        wsg[0] = wfrag[28 * 64 + lane];
        wsg[1] = wfrag[29 * 64 + lane];
    }
    float4 bfr[4];
    #pragma unroll
    for (int ft = 0; ft < 4; ++ft)
        bfr[ft] = *(const float4*)(bias + 16 * ft + 4 * g);

    #pragma unroll
    for (int st = 0; st < 4; ++st) {
        const uint stoff = (uint)st * 512u;
        uint4 B[KS];
        #pragma unroll
        for (int ks = 0; ks < KS; ++ks) {
            if (DIRB && ks == KS - 1) B[ks] = dirB[st];
            else B[ks] = *(const uint4*)&S[ro[ks] + stoff];             // ds_read_b128
        }
        f32x4 acc[4];
        #pragma unroll
        for (int ft = 0; ft < 4; ++ft)
            acc[ft] = (f32x4){bfr[ft].x, bfr[ft].y, bfr[ft].z, bfr[ft].w};
        f32x4 sacc;
        if constexpr (SIGMA) sacc = (f32x4){(g == 0) ? bd0 : 0.0f, 0.0f, 0.0f, 0.0f};
        #pragma unroll
        for (int ks = 0; ks < KS; ++ks) {
            short8 bv = __builtin_bit_cast(short8, B[ks]);
            #pragma unroll
            for (int ft = 0; ft < 4; ++ft)
                acc[ft] = __builtin_amdgcn_mfma_f32_16x16x32_bf16(
                    __builtin_bit_cast(short8, wf[ks * 4 + ft]), bv, acc[ft], 0, 0, 0);
            if constexpr (SIGMA) {
                if (ks < 2)                    // sigma over h2 only (not dirB)
                    sacc = __builtin_amdgcn_mfma_f32_16x16x32_bf16(
                        __builtin_bit_cast(short8, wsg[ks]), bv, sacc, 0, 0, 0);
            }
        }
        // D layout: col = lane&15 = sample, row = 4g + reg = out-feature.
        #pragma unroll
        for (int ft = 0; ft < 4; ++ft) {
            f32x2 lo = {acc[ft][0], acc[ft][1]};
            f32x2 hi = {acc[ft][2], acc[ft][3]};
            if constexpr (RELU) {
                lo = __builtin_elementwise_max(lo, (f32x2){0.0f, 0.0f});  // v_pk_max_f32
                hi = __builtin_elementwise_max(hi, (f32x2){0.0f, 0.0f});
            }
            uint2 v = make_uint2(packbf(lo.x, lo.y), packbf(hi.x, hi.y));
            *(uint2*)&S[wo[ft] + stoff] = v;                            // ds_write_b64
        }
        if constexpr (SIGMA) sigout[st] = sacc[0];
    }
}

__global__ __launch_bounds__(256, 4) void fused_mlp(
    const float* __restrict__ rays_o, const float* __restrict__ viewdirs,
    const float* __restrict__ t_starts, const float* __restrict__ t_ends,
    const float* __restrict__ b1, const float* __restrict__ b2,
    const float* __restrict__ bd, const float* __restrict__ b34,
    const float* __restrict__ br2,
    const int* __restrict__ ridx, const uint4* __restrict__ wfrag,
    const uint4* __restrict__ dtab, uint2* __restrict__ rgba,
    float* __restrict__ tmarr, int* __restrict__ start, int* __restrict__ end)
{
    __shared__ uint S[8192];          // 32768 B exactly

    const int tid = threadIdx.x;
    const int w = tid >> 6, lane = tid & 63;
    const int g = lane >> 4, s = lane & 15;
    const uint sm = (uint)(s & 7);
    const uint wgb = (uint)w * 2048u;                 // wave base (4 groups x 512)
    const uint rowb = wgb + (uint)s * 32u;            // row s of group 0
    const int sb0 = blockIdx.x * 256 + w * 64;

    // ---- ridx for this thread's 4 B-samples (st, s) + own sample (st=g) ----
    int ridx4[4];
    #pragma unroll
    for (int st = 0; st < 4; ++st) ridx4[st] = ridx[sb0 + st * 16 + s];
    uint4 dirB[4];
    #pragma unroll
    for (int st = 0; st < 4; ++st) dirB[st] = dtab[(size_t)ridx4[st] * 4 + g];

    const int si = sb0 + g * 16 + s;
    const int rr = ridx4[g];

    // ---- segment bounds for own sample (folded find_bounds) ----
    {
        int r_prev = ridx[(si == 0) ? 0 : si - 1];
        int r_next = ridx[(si == NS - 1) ? NS - 1 : si + 1];
        if (si == 0 || r_prev != rr) start[rr] = si;
        if (si == NS - 1 || r_next != rr) end[rr] = si + 1;
    }

    float ts = t_starts[si], te = t_ends[si];
    float tm = 0.5f * (ts + te), dtv = te - ts;
    float dx = viewdirs[3 * rr + 0], dy = viewdirs[3 * rr + 1], dz = viewdirs[3 * rr + 2];
    float px = rays_o[3 * rr + 0] + dx * tm;
    float py = rays_o[3 * rr + 1] + dy * tm;
    float pz = rays_o[3 * rr + 2] + dz * tm;
    tmarr[si] = tm;                                   // render reads this (coalesced)

    // Per-thread swizzled base addresses:
    const uint ownbase = wgb + (uint)g * 512u + (uint)s * 32u;  // own sample's row
    uint ro[2], wo[4];
    #pragma unroll
    for (int ks = 0; ks < 2; ++ks)
        ro[ks] = rowb + 4u * (((uint)(g + 4 * ks)) ^ sm);
    #pragma unroll
    for (int ft = 0; ft < 4; ++ft)
        wo[ft] = rowb + 4u * (((uint)(2 * ft + (g >> 1))) ^ sm) + 2u * (uint)(g & 1);

    // ---- posenc(pts,10), x/y packed (v_pk_* f32), z scalar -> 8 swizzled chunks ----
    {
        float enc[64];
        enc[0] = px; enc[1] = py; enc[2] = pz;
        f32x2 sxy = {__sinf(px), __sinf(py)};
        f32x2 cxy = {__cosf(px), __cosf(py)};
        float sz = __sinf(pz), cz = __cosf(pz);
        #pragma unroll
        for (int l = 0; l < 10; ++l) {
            enc[3 + 6 * l + 0] = sxy.x; enc[3 + 6 * l + 1] = sxy.y; enc[3 + 6 * l + 2] = sz;
            enc[3 + 6 * l + 3] = cxy.x; enc[3 + 6 * l + 4] = cxy.y; enc[3 + 6 * l + 5] = cz;
            f32x2 nsxy = 2.0f * sxy * cxy;
            cxy = 1.0f - 2.0f * sxy * sxy;
            float nsz = 2.0f * sz * cz;
            cz = fmaf(-2.0f * sz, sz, 1.0f);
            sxy = nsxy; sz = nsz;
        }
        enc[63] = 0.0f;
        #pragma unroll
        for (int ch = 0; ch < 8; ++ch) {
            uint4 q = make_uint4(packbf(enc[8 * ch + 0], enc[8 * ch + 1]),
                                 packbf(enc[8 * ch + 2], enc[8 * ch + 3]),
                                 packbf(enc[8 * ch + 4], enc[8 * ch + 5]),
                                 packbf(enc[8 * ch + 6], enc[8 * ch + 7]));
            *(uint4*)&S[ownbase + 4u * (((uint)ch) ^ sm)] = q;          // ds_write_b128
        }
    }

    float sig4[4];
    float bd0 = bd[0];
    uint4 dummy[4];

    dense_layer<2, true,  false, false>(S, wfrag,  0, b1,  0.0f, ro, wo, lane, dummy, sig4);
    dense_layer<2, true,  false, false>(S, wfrag,  8, b2,  0.0f, ro, wo, lane, dummy, sig4);
    // merged L3+L4: hd = relu(h2@W34 + dirB@Wr1b + b34); sigma from h2 (ks<2)
    dense_layer<3, true,  true,  true >(S, wfrag, 16, b34, bd0,  ro, wo, lane, dirB, sig4);

    // ---- rgb tile + epilogue ----
    {
        uint4 wr0 = wfrag[30 * 64 + lane], wr1f = wfrag[31 * 64 + lane];
        float c0 = br2[0], c1 = br2[1], c2 = br2[2];
        #pragma unroll
        for (int st = 0; st < 4; ++st) {
            const uint stoff = (uint)st * 512u;
            uint4 B0 = *(const uint4*)&S[ro[0] + stoff];           // chunks g
            uint4 B1 = *(const uint4*)&S[ro[1] + stoff];           // chunks g+4
            f32x4 acc = (g == 0) ? (f32x4){c0, c1, c2, 0.0f}
                                 : (f32x4){0.0f, 0.0f, 0.0f, 0.0f};
            acc = __builtin_amdgcn_mfma_f32_16x16x32_bf16(
                __builtin_bit_cast(short8, wr0), __builtin_bit_cast(short8, B0), acc, 0, 0, 0);
            acc = __builtin_amdgcn_mfma_f32_16x16x32_bf16(
                __builtin_bit_cast(short8, wr1f), __builtin_bit_cast(short8, B1), acc, 0, 0, 0);
            // dtv of sample (st, lane&15) lives in lane st*16+(lane&15)
            float dte = __shfl(dtv, st * 16 + (lane & 15));
            if (lane < 16) {
                float sg = fmaxf(sig4[st], 0.0f);   // g==0 lane holds sigma of (st, lane)
                float alpha = 1.0f - __expf(-sg * dte);
                float r0 = 1.0f / (1.0f + __expf(-acc[0]));
                float r1 = 1.0f / (1.0f + __expf(-acc[1]));
                float r2 = 1.0f / (1.0f + __expf(-acc[2]));
                uint2 o;
                o.x = packbf(r0, r1);
                o.y = packbf(r2, alpha);
                rgba[sb0 + st * 16 + lane] = o;
            }
        }
    }
}

__global__ void render_kernel(const uint2* __restrict__ rgba,
                              const float* __restrict__ tmarr,
                              const int* __restrict__ start,
                              const int* __restrict__ end,
                              float* __restrict__ out)
{
    int r = blockIdx.x * blockDim.x + threadIdx.x;
    if (r >= NR) return;
    int sb = start[r], e = end[r];
    float T = 1.0f, c0 = 0.0f, c1 = 0.0f, c2 = 0.0f, op = 0.0f, dp = 0.0f;
    for (int i = sb; i < e; ++i) {
        uint2 q = rgba[i];
        float tmid = tmarr[i];
        float vr = bflo(q.x & 0xffffu), vg = bflo(q.x >> 16);
        float vb = bflo(q.y & 0xffffu), va = bflo(q.y >> 16);
        float wgt = T * va;
        c0 += wgt * vr; c1 += wgt * vg; c2 += wgt * vb;
        op += wgt; dp += wgt * tmid;
        T *= (1.0f - va);
    }
    float bg = 1.0f - op;
    c0 += bg; c1 += bg; c2 += bg;
    out[3 * r + 0] = c0;
    out[3 * r + 1] = c1;
    out[3 * r + 2] = c2;
    out[3 * NR + r] = op;
    out[4 * NR + r] = dp;
}

extern "C" void kernel_launch(void* const* d_in, const int* in_sizes, int n_in,
                              void* d_out, int out_size, void* d_ws, size_t ws_size,
                              hipStream_t stream) {
    const float* rays_o   = (const float*)d_in[0];
    const float* viewdirs = (const float*)d_in[1];
    const float* t_starts = (const float*)d_in[2];
    const float* t_ends   = (const float*)d_in[3];
    const float* W1  = (const float*)d_in[4];
    const float* b1  = (const float*)d_in[5];
    const float* W2  = (const float*)d_in[6];
    const float* b2  = (const float*)d_in[7];
    const float* Wd  = (const float*)d_in[8];
    const float* bd  = (const float*)d_in[9];
    const float* Wf  = (const float*)d_in[10];
    const float* bf_ = (const float*)d_in[11];
    const float* Wr1 = (const float*)d_in[12];
    const float* br1 = (const float*)d_in[13];
    const float* Wr2 = (const float*)d_in[14];
    const float* br2 = (const float*)d_in[15];
    const int* ridx  = (const int*)d_in[16];
    float* out = (float*)d_out;

    char* ws = (char*)d_ws;
    uint2* rgba  = (uint2*)ws;
    float* tmarr = (float*)(ws + (size_t)NS * 8);
    int* start   = (int*)(ws + (size_t)NS * 12);
    int* end     = start + NR;
    uint4* wfrag = (uint4*)(ws + (size_t)NS * 12 + (size_t)NR * 8);
    float* b34   = (float*)(ws + (size_t)NS * 12 + (size_t)NR * 8 + 32 * 64 * 16);
    uint4* dtab  = (uint4*)(ws + (size_t)NS * 12 + (size_t)NR * 8 + 32 * 64 * 16 + 256);

    setup_kernel<<<521, 256, 0, stream>>>(viewdirs, dtab, start, end,
                                          W1, W2, Wf, Wr1, Wd, Wr2, bf_, br1,
                                          wfrag, b34);
    fused_mlp<<<NS / 256, 256, 0, stream>>>(
        rays_o, viewdirs, t_starts, t_ends,
        b1, b2, bd, b34, br2, ridx, wfrag, dtab, rgba, tmarr, start, end);
    render_kernel<<<NR / 256, 256, 0, stream>>>(rgba, tmarr, start, end, out);
}